// Round 8
// baseline (293.356 us; speedup 1.0000x reference)
//
#include <hip/hip_runtime.h>

typedef unsigned short u16;
typedef __attribute__((ext_vector_type(8))) short bf16x8;
typedef __attribute__((ext_vector_type(4))) short bf16x4;
typedef __attribute__((ext_vector_type(4))) float f32x4;

// ---------- helpers ----------
__device__ __forceinline__ u16 f2bf(float f) {
  unsigned u = __float_as_uint(f);
  u += 0x7FFFu + ((u >> 16) & 1u);   // RNE
  return (u16)(u >> 16);
}
__device__ __forceinline__ unsigned pack2(float a, float b) {
  return (unsigned)f2bf(a) | ((unsigned)f2bf(b) << 16);
}
#if __has_builtin(__builtin_amdgcn_cvt_pk_bf16_f32)
typedef __attribute__((ext_vector_type(2))) __bf16 bf16v2;
__device__ __forceinline__ unsigned cvt_pk(float a, float b) {
  bf16v2 v = __builtin_amdgcn_cvt_pk_bf16_f32(a, b);
  return __builtin_bit_cast(unsigned, v);
}
#else
__device__ __forceinline__ unsigned cvt_pk(float a, float b) { return pack2(a, b); }
#endif
__device__ __forceinline__ uint4 pack8(float4 a, float4 b) {
  uint4 r;
  r.x = cvt_pk(a.x, a.y); r.y = cvt_pk(a.z, a.w);
  r.z = cvt_pk(b.x, b.y); r.w = cvt_pk(b.z, b.w);
  return r;
}
__device__ __forceinline__ void gload16(const void* g, void* l) {
  __builtin_amdgcn_global_load_lds(
      (const __attribute__((address_space(1))) void*)g,
      (__attribute__((address_space(3))) void*)l, 16, 0, 0);
}
// 16x16x16 bf16 MFMA (A-frag layout == 16x16 C/D layout -> P stays in regs)
__device__ __forceinline__ f32x4 mfma16(bf16x4 a, bf16x4 b, f32x4 c) {
#if __has_builtin(__builtin_amdgcn_mfma_f32_16x16x16bf16_1k)
  return __builtin_amdgcn_mfma_f32_16x16x16bf16_1k(a, b, c, 0, 0, 0);
#elif __has_builtin(__builtin_amdgcn_mfma_f32_16x16x16_bf16)
  return __builtin_amdgcn_mfma_f32_16x16x16_bf16(a, b, c, 0, 0, 0);
#else
  asm volatile("v_mfma_f32_16x16x16_bf16 %0, %1, %2, %0\n\ts_nop 2"
               : "+v"(c) : "v"(a), "v"(b));
  return c;
#endif
}

// ---------- fused prep: cvt x -> bf16 | transpose Wq/Wk/Wv | cvt Wp ----------
__global__ __launch_bounds__(256) void prep(
    const float* __restrict__ x, u16* __restrict__ xbf,
    const float* __restrict__ Wq, const float* __restrict__ Wk,
    const float* __restrict__ Wv, u16* __restrict__ wt,
    const float* __restrict__ Wp, u16* __restrict__ wpbf) {
  const int tid = threadIdx.x;
  const int b = blockIdx.x;
  __shared__ __align__(16) u16 tile[64 * 72];
  if (b < 4096) {
    const size_t i = (size_t)b * 256 + tid;
    const float4* p = (const float4*)(x + i * 8);
    *(uint4*)(xbf + i * 8) = pack8(p[0], p[1]);
  } else if (b < 4864) {
    const int idx = b - 4096;
    const int w = idx >> 8;                 // which weight
    const int mat = (idx >> 4) & 15;        // head
    const int r0 = (idx & 15) * 64;         // row block
    const float* src = (w == 0 ? Wq : (w == 1 ? Wk : Wv)) + (size_t)mat * 1024 * 64;
    u16* dst = wt + (size_t)w * 1024 * 1024 + (size_t)mat * 1024 * 64;
#pragma unroll
    for (int i = 0; i < 2; ++i) {
      const int c = tid + i * 256;
      const int r = c >> 3, off = (c & 7) * 8;
      const float* p = src + (size_t)(r0 + r) * 64 + off;
      *(uint4*)(&tile[r * 72 + off]) = pack8(*(const float4*)p, *(const float4*)(p + 4));
    }
    __syncthreads();
#pragma unroll
    for (int i = 0; i < 2; ++i) {
      const int c = tid + i * 256;
      const int d = c >> 3, roff = (c & 7) * 8;
      bf16x8 v;
#pragma unroll
      for (int j = 0; j < 8; ++j) v[j] = (short)tile[(roff + j) * 72 + d];
      *(bf16x8*)(dst + (size_t)d * 1024 + r0 + roff) = v;
    }
  } else {
    const size_t i = (size_t)(b - 4864) * 256 + tid;
    const float4* p = (const float4*)(Wp + i * 8);
    *(uint4*)(wpbf + i * 8) = pack8(p[0], p[1]);
  }
}

// ---------- gemm_bt: BK=64 (half the barriers of m97's BK=32) ----------
// MODE 0: o0=Q (PRE-SCALED by 0.125*log2e) [B,H,T,D] linear;
//         o1=K in granule-column-major 64x64 TILES;
//         o2=V^T in granule-column-major 64x64 tiles.
// MODE 1: fout[M,1024] FP32 + bias bp.
//
// Tile layouts (per bh, per 64-t tile of 4096 u16), derived FROM the attn
// fragment reads so the attn stage is a LINEAR tile copy:
//   K element (t,d)      at u16  (d>>3)*512 + (t&63)*8 + (d&7)
//   V^T element (d,tl)   at u16  (tl>>3)*512 + d*8 + ((tl>>2)&1)*4 + (tl&3)
template <int MODE>
__global__ __launch_bounds__(256) void gemm_bt(
    const u16* __restrict__ A, const u16* __restrict__ BT,
    u16* __restrict__ o0, u16* __restrict__ o1, u16* __restrict__ o2,
    float* __restrict__ fout, const float* __restrict__ bp) {
  __shared__ __align__(16) u16 As[2][128 * 32];
  __shared__ __align__(16) u16 Bs[2][128 * 32];
  const int tid = threadIdx.x;
  const int lane = tid & 63, wv = tid >> 6;
  const int g = lane >> 4, ln = lane & 15;
  const int wm = wv >> 1, wn = wv & 1;
  const int m0 = blockIdx.x * 128, n0 = blockIdx.y * 128;

  const f32x4 fz = {0.f, 0.f, 0.f, 0.f};
  f32x4 acc[4][4];
#pragma unroll
  for (int i = 0; i < 4; ++i)
#pragma unroll
    for (int j = 0; j < 4; ++j) acc[i][j] = fz;

  for (int k0 = 0; k0 < 1024; k0 += 64) {
    __syncthreads();
#pragma unroll
    for (int hf = 0; hf < 2; ++hf)
#pragma unroll
      for (int j = 0; j < 2; ++j) {
        const int c = j * 256 + tid;          // 0..511
        const int r = c >> 2, off = (c & 3) * 8;
        gload16(A + (size_t)(m0 + r) * 1024 + k0 + hf * 32 + off, &As[hf][c * 8]);
        gload16(BT + (size_t)(n0 + r) * 1024 + k0 + hf * 32 + off, &Bs[hf][c * 8]);
      }
    __syncthreads();
#pragma unroll
    for (int hf = 0; hf < 2; ++hf) {
      bf16x8 af[4], bfr[4];
#pragma unroll
      for (int rt = 0; rt < 4; ++rt)
        af[rt] = *(const bf16x8*)(&As[hf][(wm * 64 + rt * 16 + ln) * 32 + g * 8]);
#pragma unroll
      for (int ct = 0; ct < 4; ++ct)
        bfr[ct] = *(const bf16x8*)(&Bs[hf][(wn * 64 + ct * 16 + ln) * 32 + g * 8]);
#pragma unroll
      for (int rt = 0; rt < 4; ++rt)
#pragma unroll
        for (int ct = 0; ct < 4; ++ct)
          acc[rt][ct] = __builtin_amdgcn_mfma_f32_16x16x32_bf16(af[rt], bfr[ct],
                                                                acc[rt][ct], 0, 0, 0);
    }
  }

  if (MODE == 0) {
    const int which = n0 >> 10;
    const int nl0 = (n0 & 1023) + wn * 64;
    const float qs = (which == 0) ? 0.1803368801f : 1.0f;  // 0.125*log2(e) for Q
    if (which < 2) {
#pragma unroll
      for (int rt = 0; rt < 4; ++rt)
#pragma unroll
        for (int ct = 0; ct < 4; ++ct) {
          const int nl = nl0 + ct * 16 + ln;
          const int h = nl >> 6, d = nl & 63;
          const unsigned p01 = cvt_pk(acc[rt][ct][0] * qs, acc[rt][ct][1] * qs);
          const unsigned p23 = cvt_pk(acc[rt][ct][2] * qs, acc[rt][ct][3] * qs);
          const u16 vv[4] = {(u16)p01, (u16)(p01 >> 16), (u16)p23, (u16)(p23 >> 16)};
#pragma unroll
          for (int r = 0; r < 4; ++r) {
            const int m = m0 + wm * 64 + rt * 16 + 4 * g + r;
            const int b = m >> 11, t = m & 2047;
            const size_t bh_base = (size_t)(b * 16 + h) * 131072;
            if (which == 0) {
              o0[bh_base + (size_t)t * 64 + d] = vv[r];
            } else {
              o1[bh_base + (size_t)(t >> 6) * 4096 + (d >> 3) * 512 +
                 (t & 63) * 8 + (d & 7)] = vv[r];
            }
          }
        }
    } else {
      // V^T tiles: uint2 (4 consecutive t at fixed d) = half a granule
#pragma unroll
      for (int rt = 0; rt < 4; ++rt) {
        const int tb = m0 + wm * 64 + rt * 16 + 4 * g;  // multiple of 4
        const int b = tb >> 11, t = tb & 2047;
        const int tile = t >> 6, tl = t & 63;
#pragma unroll
        for (int ct = 0; ct < 4; ++ct) {
          const int nl = nl0 + ct * 16 + ln;
          const int h = nl >> 6, d = nl & 63;
          uint2 pv;
          pv.x = cvt_pk(acc[rt][ct][0], acc[rt][ct][1]);
          pv.y = cvt_pk(acc[rt][ct][2], acc[rt][ct][3]);
          *(uint2*)(o2 + (size_t)(b * 16 + h) * 131072 + (size_t)tile * 4096 +
                    (tl >> 3) * 512 + d * 8 + ((tl >> 2) & 1) * 4) = pv;
        }
      }
    }
  } else {
#pragma unroll
    for (int ct = 0; ct < 4; ++ct) {
      const int n = n0 + wn * 64 + ct * 16 + ln;
      const float bias = bp[n];
#pragma unroll
      for (int rt = 0; rt < 4; ++rt)
#pragma unroll
        for (int r = 0; r < 4; ++r) {
          const int m = m0 + wm * 64 + rt * 16 + 4 * g + r;
          fout[(size_t)m * 1024 + n] = acc[rt][ct][r] + bias;
        }
    }
  }
}

// ---------- flash attention: 2-tile windows (KVBLK=128), depth-1 pipeline ----
// r5 post-mortem: three different schedules (2-barrier store, 512-thr pair,
// 3-buf counted-vmcnt) ALL land 83-87us. Counters close: VALUBusy 58% +
// MfmaUtil 30% ~= 88% combined CU pipe activity -> near issue-saturation for
// the CURRENT overlap level; schedule shape is not the lever. The one axis
// never varied is WITHIN-WAVE ILP: each wave ran one tile's serial
// QK->exp->PV chain at a time. r6/r7: process TWO k-tiles per barrier window
// so tile-b MFMA overlaps tile-a exp (separate pipes), and barriers halve
// (34 -> 17 for the longest block). Floor if overlap is perfect:
// max(VALU 115K, MFMA 60K, DS 55K) cy ~= 48us.
//  - same granule-tiled K/V producer layout (r5-verified)
//  - same two-raw-barrier + counted-vmcnt protocol (r5-verified), depth 1
//    (8 loads/window; vmcnt(8) leaves next window in flight)
//  - s_setprio(1) around both MFMA clusters (attn-proven +4-7%, m191)
//  - LDS 64KB -> 2 blocks/CU; grid (64,16), qi=15-blockIdx.y (LPT)
// (r6 and r7 benches were infra failures - "container failed twice" - with
//  no kernel signal. Bounds/deadlock audit clean; third submission. If this
//  infra-fails again, revert to r5-verified kernel + GEMM work instead.)
// S^T = K Q^T; unnormalized softmax (Q pre-scaled); l via ones-MFMA.
__global__ __launch_bounds__(256) void attn_kernel(
    const u16* __restrict__ Q, const u16* __restrict__ K,
    const u16* __restrict__ VT, u16* __restrict__ AO) {
  const int tid = threadIdx.x;
  const int wv = tid >> 6, lane = tid & 63, g = lane >> 4, ln = lane & 15;
  const int bh = blockIdx.x;
  const int qi = 15 - blockIdx.y;            // big segments first (LPT)
  const u16* Qb = Q + (size_t)bh * 131072;
  const u16* Kb = K + (size_t)bh * 131072;
  const u16* Vb = VT + (size_t)bh * 131072;

  __shared__ __align__(16) u16 KV[2][2][2][4096];  // [buf][tile][K|V] 64KB

  const int b = bh >> 4, h = bh & 15;
  const short ob = 0x3F80;
  const bf16x4 ones = {ob, ob, ob, ob};
  const f32x4 fz = {0.f, 0.f, 0.f, 0.f};

  const int q0 = qi * 128;
  const int nt = 2 * qi + 2;               // staged tiles (ALWAYS even)
  const int NW = nt >> 1;                  // 2-tile windows
  const int ntw = 2 * qi + 1 + (wv >> 1);  // this wave's compute tiles

  const int L0 = tid, L1 = tid + 256;      // 16B chunk ids of an 8KB tile

  // Q fragments (4 b128 VMEM loads; drained by the w=0 vmcnt(8))
  bf16x8 qa[2][2];
#pragma unroll
  for (int rt = 0; rt < 2; ++rt) {
    const int row = q0 + wv * 32 + rt * 16 + ln;
#pragma unroll
    for (int hh = 0; hh < 2; ++hh)
      qa[rt][hh] = *(const bf16x8*)(Qb + (size_t)row * 64 + hh * 32 + g * 8);
  }

#define STAGE(buf, w_)                                                \
  {                                                                   \
    const u16* ka_ = Kb + (size_t)(2 * (w_)) * 4096;                  \
    const u16* va_ = Vb + (size_t)(2 * (w_)) * 4096;                  \
    gload16(ka_ + L0 * 8, &KV[buf][0][0][L0 * 8]);                    \
    gload16(ka_ + L1 * 8, &KV[buf][0][0][L1 * 8]);                    \
    gload16(va_ + L0 * 8, &KV[buf][0][1][L0 * 8]);                    \
    gload16(va_ + L1 * 8, &KV[buf][0][1][L1 * 8]);                    \
    gload16(ka_ + 4096 + L0 * 8, &KV[buf][1][0][L0 * 8]);             \
    gload16(ka_ + 4096 + L1 * 8, &KV[buf][1][0][L1 * 8]);             \
    gload16(va_ + 4096 + L0 * 8, &KV[buf][1][1][L0 * 8]);             \
    gload16(va_ + 4096 + L1 * 8, &KV[buf][1][1][L1 * 8]);             \
  }

  // prologue: stage window 0
  STAGE(0, 0);

  f32x4 oacc[2][4], lacc[2];
#pragma unroll
  for (int rt = 0; rt < 2; ++rt) {
    lacc[rt] = fz;
#pragma unroll
    for (int dt = 0; dt < 4; ++dt) oacc[rt][dt] = fz;
  }

  for (int w = 0; w < NW; ++w) {
    __builtin_amdgcn_s_barrier();          // all waves done with buf (w-1)&1
    __builtin_amdgcn_sched_barrier(0);
    if (w + 1 < NW) {
      STAGE((w + 1) & 1, w + 1);
      asm volatile("s_waitcnt vmcnt(8)" ::: "memory");  // window w landed (mine)
    } else {
      asm volatile("s_waitcnt vmcnt(0)" ::: "memory");
    }
    __builtin_amdgcn_sched_barrier(0);
    __builtin_amdgcn_s_barrier();          // ALL waves' window-w loads landed
    __builtin_amdgcn_sched_barrier(0);
    const int cur = w & 1;

    // ---- S^T = K Q^T for both tiles (independent chains -> ILP)
    f32x4 sfT[2][2][4];
    __builtin_amdgcn_s_setprio(1);
#pragma unroll
    for (int hf = 0; hf < 2; ++hf) {
      if (2 * w + hf < ntw) {
        const u16* Ksb = &KV[cur][hf][0][0];
#pragma unroll
        for (int st = 0; st < 4; ++st) {
          const bf16x8 kb0 = *(const bf16x8*)(Ksb + (g * 64 + st * 16 + ln) * 8);
          const bf16x8 kb1 =
              *(const bf16x8*)(Ksb + ((g + 4) * 64 + st * 16 + ln) * 8);
#pragma unroll
          for (int rt = 0; rt < 2; ++rt) {
            sfT[hf][rt][st] = __builtin_amdgcn_mfma_f32_16x16x32_bf16(
                kb0, qa[rt][0], fz, 0, 0, 0);
            sfT[hf][rt][st] = __builtin_amdgcn_mfma_f32_16x16x32_bf16(
                kb1, qa[rt][1], sfT[hf][rt][st], 0, 0, 0);
          }
        }
      }
    }
    __builtin_amdgcn_s_setprio(0);

    // ---- exp for both tiles (VALU; overlaps trailing MFMA of tile b)
    bf16x4 pa[2][2][4];
#pragma unroll
    for (int hf = 0; hf < 2; ++hf) {
      const int kt = 2 * w + hf;
      if (kt < ntw) {
        const bool diag = (kt == ntw - 1);
        const int s0 = kt * 64;
#pragma unroll
        for (int rt = 0; rt < 2; ++rt) {
          const int qloc = wv * 32 + rt * 16 + ln;   // q - q0
#pragma unroll
          for (int st = 0; st < 4; ++st) {
            float e[4];
#pragma unroll
            for (int r = 0; r < 4; ++r)
              e[r] = __builtin_amdgcn_exp2f(sfT[hf][rt][st][r]);
            if (diag) {
              const int sloc = s0 - q0 + st * 16 + 4 * g;  // s - q0
#pragma unroll
              for (int r = 0; r < 4; ++r)
                if (sloc + r > qloc) e[r] = 0.f;
            }
            uint2 packed = {cvt_pk(e[0], e[1]), cvt_pk(e[2], e[3])};
            pa[hf][rt][st] = __builtin_bit_cast(bf16x4, packed);
          }
        }
      }
    }

    // ---- O += P V ; l += P . ones for both tiles
    __builtin_amdgcn_s_setprio(1);
#pragma unroll
    for (int hf = 0; hf < 2; ++hf) {
      if (2 * w + hf < ntw) {
        const u16* Vsb = &KV[cur][hf][1][0];
#pragma unroll
        for (int st = 0; st < 4; ++st) {
#pragma unroll
          for (int dt = 0; dt < 4; ++dt) {
            const bf16x4 vb = *(const bf16x4*)(
                Vsb + ((st * 2 + (g >> 1)) * 64 + dt * 16 + ln) * 8 + (g & 1) * 4);
#pragma unroll
            for (int rt = 0; rt < 2; ++rt)
              oacc[rt][dt] = mfma16(pa[hf][rt][st], vb, oacc[rt][dt]);
          }
#pragma unroll
          for (int rt = 0; rt < 2; ++rt)
            lacc[rt] = mfma16(pa[hf][rt][st], ones, lacc[rt]);
        }
      }
    }
    __builtin_amdgcn_s_setprio(0);
  }
#undef STAGE
  // epilogue
#pragma unroll
  for (int rt = 0; rt < 2; ++rt) {
    float linv[4];
#pragma unroll
    for (int r = 0; r < 4; ++r) linv[r] = 1.f / lacc[rt][r];
#pragma unroll
    for (int dt = 0; dt < 4; ++dt) {
      const unsigned p01 =
          cvt_pk(oacc[rt][dt][0] * linv[0], oacc[rt][dt][1] * linv[1]);
      const unsigned p23 =
          cvt_pk(oacc[rt][dt][2] * linv[2], oacc[rt][dt][3] * linv[3]);
      const u16 vv[4] = {(u16)p01, (u16)(p01 >> 16), (u16)p23, (u16)(p23 >> 16)};
#pragma unroll
      for (int r = 0; r < 4; ++r) {
        const int qg = q0 + wv * 32 + rt * 16 + 4 * g + r;
        AO[(size_t)(b * 2048 + qg) * 1024 + h * 64 + dt * 16 + ln] = vv[r];
      }
    }
  }
}

// ---------- launch ----------
// Inputs FP32, output FP32; internal bf16. ws (72 MB):
//   [0,16M): xbf (phase 1) then AO (phase 2)
//   [16,22M): wt    [22,24M): wpbf
//   Q [24,40M)   K [40,56M)   VT [56,72M)
extern "C" void kernel_launch(void* const* d_in, const int* in_sizes, int n_in,
                              void* d_out, int out_size, void* d_ws, size_t ws_size,
                              hipStream_t stream) {
  const float* x  = (const float*)d_in[0];
  const float* Wq = (const float*)d_in[1];
  const float* Wk = (const float*)d_in[2];
  const float* Wv = (const float*)d_in[3];
  const float* Wp = (const float*)d_in[4];
  const float* bp = (const float*)d_in[5];
  float* out = (float*)d_out;

  char* ws = (char*)d_ws;
  const size_t MB = 1048576;
  u16* xbf  = (u16*)(ws);
  u16* aows = (u16*)(ws);
  u16* wt   = (u16*)(ws + 16 * MB);
  u16* wpbf = (u16*)(ws + 22 * MB);
  u16* qws  = (u16*)(ws + 24 * MB);
  u16* kws  = (u16*)(ws + 40 * MB);
  u16* vtws = (u16*)(ws + 56 * MB);

  // fused prep: x->bf16, Wq/Wk/Wv -> WT[3072][1024] bf16, Wp->bf16
  prep<<<dim3(5376), 256, 0, stream>>>(x, xbf, Wq, Wk, Wv, wt, Wp, wpbf);
  // QKV projection -> Q(prescaled) linear; K,V^T in granule-column-major tiles
  gemm_bt<0><<<dim3(64, 24), 256, 0, stream>>>(xbf, wt, qws, kws, vtws,
                                               nullptr, nullptr);
  // causal flash attention -> AO [B,T,H*D] (overlays dead xbf)
  attn_kernel<<<dim3(64, 16), 256, 0, stream>>>(qws, kws, vtws, aows);
  // output projection: AO @ Wp^T + bp -> out FP32
  gemm_bt<1><<<dim3(64, 8), 256, 0, stream>>>(aows, wpbf, nullptr, nullptr,
                                              nullptr, out, bp);
}

// Round 9
// 265.169 us; speedup vs baseline: 1.1063x; 1.1063x over previous
//
#include <hip/hip_runtime.h>

typedef unsigned short u16;
typedef __attribute__((ext_vector_type(8))) short bf16x8;
typedef __attribute__((ext_vector_type(4))) short bf16x4;
typedef __attribute__((ext_vector_type(4))) float f32x4;

// ---------- helpers ----------
__device__ __forceinline__ u16 f2bf(float f) {
  unsigned u = __float_as_uint(f);
  u += 0x7FFFu + ((u >> 16) & 1u);   // RNE
  return (u16)(u >> 16);
}
__device__ __forceinline__ unsigned pack2(float a, float b) {
  return (unsigned)f2bf(a) | ((unsigned)f2bf(b) << 16);
}
#if __has_builtin(__builtin_amdgcn_cvt_pk_bf16_f32)
typedef __attribute__((ext_vector_type(2))) __bf16 bf16v2;
__device__ __forceinline__ unsigned cvt_pk(float a, float b) {
  bf16v2 v = __builtin_amdgcn_cvt_pk_bf16_f32(a, b);
  return __builtin_bit_cast(unsigned, v);
}
#else
__device__ __forceinline__ unsigned cvt_pk(float a, float b) { return pack2(a, b); }
#endif
__device__ __forceinline__ uint4 pack8(float4 a, float4 b) {
  uint4 r;
  r.x = cvt_pk(a.x, a.y); r.y = cvt_pk(a.z, a.w);
  r.z = cvt_pk(b.x, b.y); r.w = cvt_pk(b.z, b.w);
  return r;
}
__device__ __forceinline__ void gload16(const void* g, void* l) {
  __builtin_amdgcn_global_load_lds(
      (const __attribute__((address_space(1))) void*)g,
      (__attribute__((address_space(3))) void*)l, 16, 0, 0);
}
// 16x16x16 bf16 MFMA (A-frag layout == 16x16 C/D layout -> P stays in regs)
__device__ __forceinline__ f32x4 mfma16(bf16x4 a, bf16x4 b, f32x4 c) {
#if __has_builtin(__builtin_amdgcn_mfma_f32_16x16x16bf16_1k)
  return __builtin_amdgcn_mfma_f32_16x16x16bf16_1k(a, b, c, 0, 0, 0);
#elif __has_builtin(__builtin_amdgcn_mfma_f32_16x16x16_bf16)
  return __builtin_amdgcn_mfma_f32_16x16x16_bf16(a, b, c, 0, 0, 0);
#else
  asm volatile("v_mfma_f32_16x16x16_bf16 %0, %1, %2, %0\n\ts_nop 2"
               : "+v"(c) : "v"(a), "v"(b));
  return c;
#endif
}

// ---------- fused prep: cvt x -> bf16 | transpose Wq/Wk/Wv | cvt Wp ----------
__global__ __launch_bounds__(256) void prep(
    const float* __restrict__ x, u16* __restrict__ xbf,
    const float* __restrict__ Wq, const float* __restrict__ Wk,
    const float* __restrict__ Wv, u16* __restrict__ wt,
    const float* __restrict__ Wp, u16* __restrict__ wpbf) {
  const int tid = threadIdx.x;
  const int b = blockIdx.x;
  __shared__ __align__(16) u16 tile[64 * 72];
  if (b < 4096) {
    const size_t i = (size_t)b * 256 + tid;
    const float4* p = (const float4*)(x + i * 8);
    *(uint4*)(xbf + i * 8) = pack8(p[0], p[1]);
  } else if (b < 4864) {
    const int idx = b - 4096;
    const int w = idx >> 8;                 // which weight
    const int mat = (idx >> 4) & 15;        // head
    const int r0 = (idx & 15) * 64;         // row block
    const float* src = (w == 0 ? Wq : (w == 1 ? Wk : Wv)) + (size_t)mat * 1024 * 64;
    u16* dst = wt + (size_t)w * 1024 * 1024 + (size_t)mat * 1024 * 64;
#pragma unroll
    for (int i = 0; i < 2; ++i) {
      const int c = tid + i * 256;
      const int r = c >> 3, off = (c & 7) * 8;
      const float* p = src + (size_t)(r0 + r) * 64 + off;
      *(uint4*)(&tile[r * 72 + off]) = pack8(*(const float4*)p, *(const float4*)(p + 4));
    }
    __syncthreads();
#pragma unroll
    for (int i = 0; i < 2; ++i) {
      const int c = tid + i * 256;
      const int d = c >> 3, roff = (c & 7) * 8;
      bf16x8 v;
#pragma unroll
      for (int j = 0; j < 8; ++j) v[j] = (short)tile[(roff + j) * 72 + d];
      *(bf16x8*)(dst + (size_t)d * 1024 + r0 + roff) = v;
    }
  } else {
    const size_t i = (size_t)(b - 4864) * 256 + tid;
    const float4* p = (const float4*)(Wp + i * 8);
    *(uint4*)(wpbf + i * 8) = pack8(p[0], p[1]);
  }
}

// ---------- gemm_bt: BK=64 (half the barriers of m97's BK=32) ----------
// MODE 0: o0=Q (PRE-SCALED by 0.125*log2e) [B,H,T,D] linear;
//         o1=K in granule-column-major 64x64 TILES;
//         o2=V^T in granule-column-major 64x64 tiles.
// MODE 1: fout[M,1024] FP32 + bias bp.
//
// Tile layouts (per bh, per 64-t tile of 4096 u16), derived FROM the attn
// fragment reads so the attn stage is a LINEAR tile copy:
//   K element (t,d)      at u16  (d>>3)*512 + (t&63)*8 + (d&7)
//   V^T element (d,tl)   at u16  (tl>>3)*512 + d*8 + ((tl>>2)&1)*4 + (tl&3)
template <int MODE>
__global__ __launch_bounds__(256) void gemm_bt(
    const u16* __restrict__ A, const u16* __restrict__ BT,
    u16* __restrict__ o0, u16* __restrict__ o1, u16* __restrict__ o2,
    float* __restrict__ fout, const float* __restrict__ bp) {
  __shared__ __align__(16) u16 As[2][128 * 32];
  __shared__ __align__(16) u16 Bs[2][128 * 32];
  const int tid = threadIdx.x;
  const int lane = tid & 63, wv = tid >> 6;
  const int g = lane >> 4, ln = lane & 15;
  const int wm = wv >> 1, wn = wv & 1;
  const int m0 = blockIdx.x * 128, n0 = blockIdx.y * 128;

  const f32x4 fz = {0.f, 0.f, 0.f, 0.f};
  f32x4 acc[4][4];
#pragma unroll
  for (int i = 0; i < 4; ++i)
#pragma unroll
    for (int j = 0; j < 4; ++j) acc[i][j] = fz;

  for (int k0 = 0; k0 < 1024; k0 += 64) {
    __syncthreads();
#pragma unroll
    for (int hf = 0; hf < 2; ++hf)
#pragma unroll
      for (int j = 0; j < 2; ++j) {
        const int c = j * 256 + tid;          // 0..511
        const int r = c >> 2, off = (c & 3) * 8;
        gload16(A + (size_t)(m0 + r) * 1024 + k0 + hf * 32 + off, &As[hf][c * 8]);
        gload16(BT + (size_t)(n0 + r) * 1024 + k0 + hf * 32 + off, &Bs[hf][c * 8]);
      }
    __syncthreads();
#pragma unroll
    for (int hf = 0; hf < 2; ++hf) {
      bf16x8 af[4], bfr[4];
#pragma unroll
      for (int rt = 0; rt < 4; ++rt)
        af[rt] = *(const bf16x8*)(&As[hf][(wm * 64 + rt * 16 + ln) * 32 + g * 8]);
#pragma unroll
      for (int ct = 0; ct < 4; ++ct)
        bfr[ct] = *(const bf16x8*)(&Bs[hf][(wn * 64 + ct * 16 + ln) * 32 + g * 8]);
#pragma unroll
      for (int rt = 0; rt < 4; ++rt)
#pragma unroll
        for (int ct = 0; ct < 4; ++ct)
          acc[rt][ct] = __builtin_amdgcn_mfma_f32_16x16x32_bf16(af[rt], bfr[ct],
                                                                acc[rt][ct], 0, 0, 0);
    }
  }

  if (MODE == 0) {
    const int which = n0 >> 10;
    const int nl0 = (n0 & 1023) + wn * 64;
    const float qs = (which == 0) ? 0.1803368801f : 1.0f;  // 0.125*log2(e) for Q
    if (which < 2) {
#pragma unroll
      for (int rt = 0; rt < 4; ++rt)
#pragma unroll
        for (int ct = 0; ct < 4; ++ct) {
          const int nl = nl0 + ct * 16 + ln;
          const int h = nl >> 6, d = nl & 63;
          const unsigned p01 = cvt_pk(acc[rt][ct][0] * qs, acc[rt][ct][1] * qs);
          const unsigned p23 = cvt_pk(acc[rt][ct][2] * qs, acc[rt][ct][3] * qs);
          const u16 vv[4] = {(u16)p01, (u16)(p01 >> 16), (u16)p23, (u16)(p23 >> 16)};
#pragma unroll
          for (int r = 0; r < 4; ++r) {
            const int m = m0 + wm * 64 + rt * 16 + 4 * g + r;
            const int b = m >> 11, t = m & 2047;
            const size_t bh_base = (size_t)(b * 16 + h) * 131072;
            if (which == 0) {
              o0[bh_base + (size_t)t * 64 + d] = vv[r];
            } else {
              o1[bh_base + (size_t)(t >> 6) * 4096 + (d >> 3) * 512 +
                 (t & 63) * 8 + (d & 7)] = vv[r];
            }
          }
        }
    } else {
      // V^T tiles: uint2 (4 consecutive t at fixed d) = half a granule
#pragma unroll
      for (int rt = 0; rt < 4; ++rt) {
        const int tb = m0 + wm * 64 + rt * 16 + 4 * g;  // multiple of 4
        const int b = tb >> 11, t = tb & 2047;
        const int tile = t >> 6, tl = t & 63;
#pragma unroll
        for (int ct = 0; ct < 4; ++ct) {
          const int nl = nl0 + ct * 16 + ln;
          const int h = nl >> 6, d = nl & 63;
          uint2 pv;
          pv.x = cvt_pk(acc[rt][ct][0], acc[rt][ct][1]);
          pv.y = cvt_pk(acc[rt][ct][2], acc[rt][ct][3]);
          *(uint2*)(o2 + (size_t)(b * 16 + h) * 131072 + (size_t)tile * 4096 +
                    (tl >> 3) * 512 + d * 8 + ((tl >> 2) & 1) * 4) = pv;
        }
      }
    }
  } else {
#pragma unroll
    for (int ct = 0; ct < 4; ++ct) {
      const int n = n0 + wn * 64 + ct * 16 + ln;
      const float bias = bp[n];
#pragma unroll
      for (int rt = 0; rt < 4; ++rt)
#pragma unroll
        for (int r = 0; r < 4; ++r) {
          const int m = m0 + wm * 64 + rt * 16 + 4 * g + r;
          fout[(size_t)m * 1024 + n] = acc[rt][ct][r] + bias;
        }
    }
  }
}

// ---------- flash attention: ring-2 gload_lds pipeline, 5 blocks/CU ----------
// r8 post-mortem: KVBLK=128 ILP variant REGRESSED 83.6->122.6us (LDS 64KB ->
// 2 blocks/CU, occupancy 10.8%, VGPR 132; the two chains serialized anyway).
// TLP, not ILP, is the lever: r5's per-wave pipe work is ~336cy VALU (32
// v_exp @8cy dominate) + ~240cy MFMA per tile, and at 3 waves/SIMD (ring-3 =
// 48KB -> 3 blocks/CU) VALUBusy 58% == work/residency ratio: SIMDs idle ~40%
// on the serial chain. r9: RING-2 (32KB) with the SAME r5-verified
// two-raw-barrier + counted-vmcnt protocol:
//   blocks/CU 3 -> 5 (LDS 160/32; VGPR 88 allows 5 waves/SIMD), 20 waves/CU,
//   whole 1024-block grid co-resident (1280 slots) -> ragged tail absorbed.
// Pipeline depth 2 -> 1 tile: in-flight L2 latency (~200-500cy) << ~1000cy
// compute window, and 5 resident blocks hide the rest.
// vmcnt ledger: steady vmcnt(4) (tile kt+1 in flight); kt=0 drains Q+tile0;
// tail vmcnt(0). Race check: STAGE at kt targets buf (kt+1)&1, last computed
// at kt-1, protected by the top barrier of iter kt.
// Everything else byte-identical to the r5-verified kernel (passed, 266us).
// S^T = K Q^T; unnormalized softmax (Q pre-scaled); l via ones-MFMA.
__global__ __launch_bounds__(256) void attn_kernel(
    const u16* __restrict__ Q, const u16* __restrict__ K,
    const u16* __restrict__ VT, u16* __restrict__ AO) {
  const int tid = threadIdx.x;
  const int wv = tid >> 6, lane = tid & 63, g = lane >> 4, ln = lane & 15;
  const int bh = blockIdx.x;
  const int qi = 15 - blockIdx.y;            // big segments first (LPT)
  const u16* Qb = Q + (size_t)bh * 131072;
  const u16* Kb = K + (size_t)bh * 131072;
  const u16* Vb = VT + (size_t)bh * 131072;

  __shared__ __align__(16) u16 KV[2][2][4096];   // 32KB: [buf][K|V][tile]

  const int b = bh >> 4, h = bh & 15;
  const short ob = 0x3F80;
  const bf16x4 ones = {ob, ob, ob, ob};
  const f32x4 fz = {0.f, 0.f, 0.f, 0.f};

  const int q0 = qi * 128;
  const int nt = 2 * qi + 2;               // staged tiles
  const int ntw = 2 * qi + 1 + (wv >> 1);  // this wave's compute tiles

  const int L0 = tid, L1 = tid + 256;      // 16B chunk ids of the 8KB tile

  // Q fragments (4 b128 VMEM loads; drained by the kt=0 vmcnt(4))
  bf16x8 qa[2][2];
#pragma unroll
  for (int rt = 0; rt < 2; ++rt) {
    const int row = q0 + wv * 32 + rt * 16 + ln;
#pragma unroll
    for (int hh = 0; hh < 2; ++hh)
      qa[rt][hh] = *(const bf16x8*)(Qb + (size_t)row * 64 + hh * 32 + g * 8);
  }

#define STAGE(buf, tile)                                              \
  {                                                                   \
    const u16* kt_ = Kb + (size_t)(tile) * 4096;                      \
    const u16* vt_ = Vb + (size_t)(tile) * 4096;                      \
    gload16(kt_ + L0 * 8, &KV[buf][0][L0 * 8]);                       \
    gload16(kt_ + L1 * 8, &KV[buf][0][L1 * 8]);                       \
    gload16(vt_ + L0 * 8, &KV[buf][1][L0 * 8]);                       \
    gload16(vt_ + L1 * 8, &KV[buf][1][L1 * 8]);                       \
  }

  // prologue: stage tile 0 into buf 0
  STAGE(0, 0);

  f32x4 oacc[2][4], lacc[2];
#pragma unroll
  for (int rt = 0; rt < 2; ++rt) {
    lacc[rt] = fz;
#pragma unroll
    for (int dt = 0; dt < 4; ++dt) oacc[rt][dt] = fz;
  }

  for (int kt = 0; kt < nt; ++kt) {
    __builtin_amdgcn_s_barrier();          // all waves done with buf (kt+1)&1
    __builtin_amdgcn_sched_barrier(0);
    if (kt + 1 < nt) {
      STAGE((kt + 1) & 1, kt + 1);
      asm volatile("s_waitcnt vmcnt(4)" ::: "memory");   // kt+1 in flight
    } else {
      asm volatile("s_waitcnt vmcnt(0)" ::: "memory");
    }
    __builtin_amdgcn_sched_barrier(0);
    __builtin_amdgcn_s_barrier();          // ALL waves' tile-kt loads landed
    __builtin_amdgcn_sched_barrier(0);
    if (kt < ntw) {
      const int bufi = kt & 1;
      const u16* Ksb = &KV[bufi][0][0];
      const u16* Vsb = &KV[bufi][1][0];
      const int s0 = kt * 64;
      // S^T = K Q^T (first MFMA consumes fz directly: no acc zero-init)
      f32x4 sfT[2][4];
#pragma unroll
      for (int st = 0; st < 4; ++st) {
        const bf16x8 kb0 = *(const bf16x8*)(Ksb + (g * 64 + st * 16 + ln) * 8);
        const bf16x8 kb1 =
            *(const bf16x8*)(Ksb + ((g + 4) * 64 + st * 16 + ln) * 8);
#pragma unroll
        for (int rt = 0; rt < 2; ++rt) {
          sfT[rt][st] = __builtin_amdgcn_mfma_f32_16x16x32_bf16(kb0, qa[rt][0],
                                                                fz, 0, 0, 0);
          sfT[rt][st] = __builtin_amdgcn_mfma_f32_16x16x32_bf16(kb1, qa[rt][1],
                                                                sfT[rt][st], 0, 0, 0);
        }
      }
      // exp (Q pre-scaled); causal mask only on this wave's diagonal tile
      const bool diag = (kt == ntw - 1);
      bf16x4 pa[2][4];
#pragma unroll
      for (int rt = 0; rt < 2; ++rt) {
        const int qloc = wv * 32 + rt * 16 + ln;   // q - q0
#pragma unroll
        for (int st = 0; st < 4; ++st) {
          float e[4];
#pragma unroll
          for (int r = 0; r < 4; ++r) e[r] = __builtin_amdgcn_exp2f(sfT[rt][st][r]);
          if (diag) {
            const int sloc = s0 - q0 + st * 16 + 4 * g;  // s - q0
#pragma unroll
            for (int r = 0; r < 4; ++r)
              if (sloc + r > qloc) e[r] = 0.f;
          }
          uint2 packed = {cvt_pk(e[0], e[1]), cvt_pk(e[2], e[3])};
          pa[rt][st] = __builtin_bit_cast(bf16x4, packed);
        }
      }
      // O += P V ; l += P . ones
#pragma unroll
      for (int st = 0; st < 4; ++st) {
#pragma unroll
        for (int dt = 0; dt < 4; ++dt) {
          const bf16x4 vb = *(const bf16x4*)(
              Vsb + ((st * 2 + (g >> 1)) * 64 + dt * 16 + ln) * 8 + (g & 1) * 4);
#pragma unroll
          for (int rt = 0; rt < 2; ++rt)
            oacc[rt][dt] = mfma16(pa[rt][st], vb, oacc[rt][dt]);
        }
#pragma unroll
        for (int rt = 0; rt < 2; ++rt)
          lacc[rt] = mfma16(pa[rt][st], ones, lacc[rt]);
      }
    }
  }
#undef STAGE
  // epilogue
#pragma unroll
  for (int rt = 0; rt < 2; ++rt) {
    float linv[4];
#pragma unroll
    for (int r = 0; r < 4; ++r) linv[r] = 1.f / lacc[rt][r];
#pragma unroll
    for (int dt = 0; dt < 4; ++dt) {
      const unsigned p01 =
          cvt_pk(oacc[rt][dt][0] * linv[0], oacc[rt][dt][1] * linv[1]);
      const unsigned p23 =
          cvt_pk(oacc[rt][dt][2] * linv[2], oacc[rt][dt][3] * linv[3]);
      const u16 vv[4] = {(u16)p01, (u16)(p01 >> 16), (u16)p23, (u16)(p23 >> 16)};
#pragma unroll
      for (int r = 0; r < 4; ++r) {
        const int qg = q0 + wv * 32 + rt * 16 + 4 * g + r;
        AO[(size_t)(b * 2048 + qg) * 1024 + h * 64 + dt * 16 + ln] = vv[r];
      }
    }
  }
}

// ---------- launch ----------
// Inputs FP32, output FP32; internal bf16. ws (72 MB):
//   [0,16M): xbf (phase 1) then AO (phase 2)
//   [16,22M): wt    [22,24M): wpbf
//   Q [24,40M)   K [40,56M)   VT [56,72M)
extern "C" void kernel_launch(void* const* d_in, const int* in_sizes, int n_in,
                              void* d_out, int out_size, void* d_ws, size_t ws_size,
                              hipStream_t stream) {
  const float* x  = (const float*)d_in[0];
  const float* Wq = (const float*)d_in[1];
  const float* Wk = (const float*)d_in[2];
  const float* Wv = (const float*)d_in[3];
  const float* Wp = (const float*)d_in[4];
  const float* bp = (const float*)d_in[5];
  float* out = (float*)d_out;

  char* ws = (char*)d_ws;
  const size_t MB = 1048576;
  u16* xbf  = (u16*)(ws);
  u16* aows = (u16*)(ws);
  u16* wt   = (u16*)(ws + 16 * MB);
  u16* wpbf = (u16*)(ws + 22 * MB);
  u16* qws  = (u16*)(ws + 24 * MB);
  u16* kws  = (u16*)(ws + 40 * MB);
  u16* vtws = (u16*)(ws + 56 * MB);

  // fused prep: x->bf16, Wq/Wk/Wv -> WT[3072][1024] bf16, Wp->bf16
  prep<<<dim3(5376), 256, 0, stream>>>(x, xbf, Wq, Wk, Wv, wt, Wp, wpbf);
  // QKV projection -> Q(prescaled) linear; K,V^T in granule-column-major tiles
  gemm_bt<0><<<dim3(64, 24), 256, 0, stream>>>(xbf, wt, qws, kws, vtws,
                                               nullptr, nullptr);
  // causal flash attention -> AO [B,T,H*D] (overlays dead xbf)
  attn_kernel<<<dim3(64, 16), 256, 0, stream>>>(qws, kws, vtws, aows);
  // output projection: AO @ Wp^T + bp -> out FP32
  gemm_bt<1><<<dim3(64, 8), 256, 0, stream>>>(aows, wpbf, nullptr, nullptr,
                                              nullptr, out, bp);
}